// Round 16
// baseline (177.134 us; speedup 1.0000x reference)
//
#include <hip/hip_runtime.h>
#include <hip/hip_bf16.h>

#define ICN 512
#define OCN 512
#define RS    136      // padded pixel-plane row stride (cols)
#define NROW  17792    // GEMM N cols = 139*128; C plane stride
#define GUARD 144      // zero guard rows in front of XPT (max shift 137)
#define XROWS 17936    // GUARD + NROW

typedef __attribute__((ext_vector_type(8))) short short8;
typedef __attribute__((ext_vector_type(4))) float f32x4;

__device__ __forceinline__ void gload_lds16(const void* g, void* l) {
  __builtin_amdgcn_global_load_lds(
      (const __attribute__((address_space(1))) void*)g,
      (__attribute__((address_space(3))) void*)l, 16, 0, 0);
}

// raw barrier: execution sync WITHOUT vmcnt drain; compiler fences pin LDS ops
__device__ __forceinline__ void bar_raw() {
  asm volatile("" ::: "memory");
  __builtin_amdgcn_s_barrier();
  asm volatile("" ::: "memory");
}

// ---- fused demod + weight pack into MFMA A-fragment records ----
// AF record (1KB) = A-fragment for one mfma_16x16x32: rec = (tp*32+m16)*16+kc,
// lane l holds oc = m16*16 + (l&15), k-elems kc*32 + (l>>4)*8 .. +8.
__global__ __launch_bounds__(256) void wprep_k(const float* __restrict__ w,
                                               __hip_bfloat16* __restrict__ AF) {
  constexpr int WIDX[9] = {0, 2, 6, 8, 1, 7, 3, 5, 4};  // tap -> ky*3+kx
  const int oc = blockIdx.x;
  const int tid = threadIdx.x, lane = tid & 63, wv = tid >> 6;

  float v[2][9];
  float s = 0.f;
#pragma unroll
  for (int rep = 0; rep < 2; ++rep) {
    const int ic = tid + rep * 256;
    const float* wp = w + ((size_t)oc * ICN + ic) * 9;
#pragma unroll
    for (int j = 0; j < 9; ++j) { v[rep][j] = wp[j]; s += wp[j] * wp[j]; }
  }
#pragma unroll
  for (int o = 32; o > 0; o >>= 1) s += __shfl_down(s, o, 64);
  __shared__ float red[4];
  if (lane == 0) red[wv] = s;
  __syncthreads();
  const float tot = red[0] + red[1] + red[2] + red[3];
  const float scale2 = 1.0f / 4608.0f;
  const float c = sqrtf(scale2) * rsqrtf(scale2 * tot + 1e-8f);

#pragma unroll
  for (int rep = 0; rep < 2; ++rep) {
    const int ic = tid + rep * 256;
    const size_t inr = (size_t)(((oc & 15) | (((ic >> 3) & 3) << 4)) * 8 + (ic & 7));
#pragma unroll
    for (int tp = 0; tp < 9; ++tp) {
      const size_t rec = ((size_t)tp * 32 + (oc >> 4)) * 16 + (ic >> 5);
      AF[rec * 512 + inr] = __float2bfloat16(c * v[rep][WIDX[tp]]);
    }
  }
}

// ---- x -> bf16 transposed padded pixel space, via LDS transpose tile ----
__global__ __launch_bounds__(256) void packx2_k(const float* __restrict__ x,
                                                unsigned int* __restrict__ XP32) {
  const int py  = blockIdx.x;        // 0..129
  const int ic0 = blockIdx.y * 64;
  const int tid = threadIdx.x;
  const int yy  = py - 1;
  const bool rowvalid = (unsigned)yy < 128u;

  __shared__ __hip_bfloat16 T[128 * 65];   // T[xx][ic_i], padded stride 65

  if (rowvalid) {
    const float4* xr = (const float4*)(x + (size_t)ic0 * 16384 + (size_t)yy * 128);
#pragma unroll
    for (int rep = 0; rep < 8; ++rep) {
      const int idx = rep * 256 + tid;     // 0..2047
      const int x4 = idx & 31, ici = idx >> 5;
      const float4 v = xr[(size_t)ici * 4096 + x4];   // coalesced 16B/lane
      const int xx = x4 * 4;
      T[(xx + 0) * 65 + ici] = __float2bfloat16(v.x);
      T[(xx + 1) * 65 + ici] = __float2bfloat16(v.y);
      T[(xx + 2) * 65 + ici] = __float2bfloat16(v.z);
      T[(xx + 3) * 65 + ici] = __float2bfloat16(v.w);
    }
  }
  __syncthreads();

  const size_t rowbase = (size_t)(GUARD + py * 136) * 256 + (ic0 >> 1);
  for (int rep = 0; rep < 17; ++rep) {
    const int idx = rep * 256 + tid;
    const int px = idx >> 5, j = idx & 31;
    unsigned int uv = 0;
    if (rowvalid && (unsigned)(px - 1) < 128u) {
      union { __hip_bfloat16 h[2]; unsigned int u; } cv;
      cv.h[0] = T[(px - 1) * 65 + 2 * j];
      cv.h[1] = T[(px - 1) * 65 + 2 * j + 1];
      uv = cv.u;
    }
    XP32[rowbase + (size_t)px * 256 + j] = uv;   // coalesced
  }
}

// ---- zero the guard rows [0,144) and tail rows [17824,17936) of XPT ----
__global__ __launch_bounds__(256) void zguard_k(unsigned int* __restrict__ XP32) {
  const int r = blockIdx.x;                       // 0..255
  const int row = (r < 144) ? r : (r + 17680);    // 144->17824 .. 255->17935
  XP32[(size_t)row * 256 + threadIdx.x] = 0;
}

// ---- MFMA implicit GEMM, occupancy-first ----
// BM=128, BN=256, BK=64. 8 waves (2Mx4N), per-wave 64x64 out (acc 64 VGPR).
// A: direct global->VGPR coalesced fragment-record loads (AF), no LDS.
// B: LDS 2x32KB double-buffer, st-swizzle byte^=((row&7)<<4), linear dest +
// pre-swizzled source. One vmcnt(0)+s_barrier per K-step. launch_bounds(512,4)
// pins <=128 VGPR -> 2 blocks/CU (16 waves) for cross-block TLP.
__global__ __launch_bounds__(512, 4) void gemm_k(const __hip_bfloat16* __restrict__ AF,
                                                 const __hip_bfloat16* __restrict__ XPT,
                                                 __hip_bfloat16* __restrict__ C) {
  constexpr int NTt[4]   = {4, 2, 2, 1};
  constexpr int TPO[4]   = {0, 4, 6, 8};
  constexpr int SHIFT[9] = {0, 1, 136, 137, 0, 136, 0, 1, 0};
  constexpr int AR[4]    = {129, 129, 128, 128};
  constexpr int AC[4]    = {129, 128, 129, 128};

  const int n0 = blockIdx.x * 256, oc0 = blockIdx.y * 128, ph = blockIdx.z;
  const int tid = threadIdx.x, lane = tid & 63, wv = tid >> 6;
  const int wr = wv >> 2, wc = wv & 3;            // 2M x 4N wave grid
  const int lane15 = lane & 15, l7 = lane & 7;
  const int kx = (lane >> 4) * 16;                // k-byte offset of lane chunk

  __shared__ __align__(16) char lds[2 * 32768];   // B only, double-buffered

  const int T = NTt[ph] * 8;                      // K-steps of 64

  // B staging geometry (512 threads cover 256 rows x 128B in 4 gloads)
  const int r0  = tid >> 3;                       // row 0..63 within 64-row group
  const int wk0 = ((tid * 16) & 127) ^ ((r0 & 7) << 4);

  auto STG = [&](int i, char* Lb) {
    const int tp = TPO[ph] + (i >> 3);
    const size_t kb = (size_t)(i & 7) * 128;
    const char* Bg = (const char*)XPT +
                     (size_t)(GUARD + n0 - SHIFT[tp]) * 1024 + kb;
#pragma unroll
    for (int g = 0; g < 4; ++g)
      gload_lds16(Bg + (size_t)(g * 64 + r0) * 1024 + wk0,
                  Lb + g * 8192 + wv * 1024);
  };

  f32x4 acc[4][4];
#pragma unroll
  for (int m = 0; m < 4; ++m)
#pragma unroll
    for (int n = 0; n < 4; ++n) acc[m][n] = (f32x4){0.f, 0.f, 0.f, 0.f};

  STG(0, lds);
  asm volatile("s_waitcnt vmcnt(0)" ::: "memory");
  bar_raw();

  for (int i = 0; i < T; ++i) {
    const int buf = i & 1;
    const char* LB = lds + buf * 32768;
    char* Ln = lds + (buf ^ 1) * 32768;
    const int ts = (i + 1 < T) ? (i + 1) : (T - 1);   // tail: dummy re-stage
    STG(ts, Ln);                                       // flies across this step

    const int tp = TPO[ph] + (i >> 3);
    // this wave's A record base: m16 = (oc0>>4) + wr*4 + m, kc = (i&7)*2 + kh
    const char* AFt = (const char*)AF +
        ((size_t)((tp * 32 + (oc0 >> 4) + wr * 4) * 16 + (i & 7) * 2) << 10) +
        (size_t)lane * 16;

#pragma unroll
    for (int kh = 0; kh < 2; ++kh) {
      short8 bf[4], af[4];
#pragma unroll
      for (int n = 0; n < 4; ++n) {
        const int e = (wc * 64 + n * 16 + lane15) * 128 + kh * 64 + kx;
        bf[n] = *(const short8*)(LB + (e ^ (l7 << 4)));
      }
#pragma unroll
      for (int m = 0; m < 4; ++m)
        af[m] = *(const short8*)(AFt + ((size_t)(m * 16 + kh) << 10));
      __builtin_amdgcn_s_setprio(1);
#pragma unroll
      for (int m = 0; m < 4; ++m)
#pragma unroll
        for (int n = 0; n < 4; ++n)
          acc[m][n] = __builtin_amdgcn_mfma_f32_16x16x32_bf16(af[m], bf[n], acc[m][n], 0, 0, 0);
      __builtin_amdgcn_s_setprio(0);
    }

    // single cross-wave handshake per K-step: my B reads done (lgkm forced by
    // MFMA uses), my stage of buf^1 landed (vmcnt 0)
    asm volatile("s_waitcnt vmcnt(0)" ::: "memory");
    bar_raw();
  }

  // epilogue: D col = lane&15, row = (lane>>4)*4 + r; mask pad cells to zero
  const int lr = (lane >> 4) * 4, lc = lane & 15;
#pragma unroll
  for (int n = 0; n < 4; ++n) {
    const int col = n0 + wc * 64 + n * 16 + lc;
    if (col < NROW) {
      const int pa = col / 136, pb = col - pa * 136;
      const bool ok = ((unsigned)(pa - 1) < (unsigned)AR[ph]) &&
                      ((unsigned)(pb - 1) < (unsigned)AC[ph]);
#pragma unroll
      for (int m = 0; m < 4; ++m)
#pragma unroll
        for (int r = 0; r < 4; ++r) {
          const int row = oc0 + wr * 64 + m * 16 + lr + r;
          C[((size_t)(ph * OCN + row)) * NROW + col] =
              __float2bfloat16(ok ? acc[m][n][r] : 0.f);
        }
    }
  }
}

// ---- vectorized depthwise 4x4 blur: 8 outputs/thread, branch-free ----
struct __align__(8) U4 { unsigned int w[4]; };

__global__ __launch_bounds__(256) void blur2_k(const unsigned short* __restrict__ C,
                                               float* __restrict__ out) {
  const int tid = threadIdx.x;
  const int t  = tid & 31;                  // col block: n in [8t, 8t+8)
  const int m  = blockIdx.x * 8 + (tid >> 5);
  const int oc = blockIdx.y;
  const float cfv[4] = {0.25f, 0.75f, 0.75f, 0.25f};

  float acc[8];
#pragma unroll
  for (int s = 0; s < 8; ++s) acc[s] = 0.f;

#pragma unroll
  for (int i = 0; i < 4; ++i) {
    const int u  = m - 1 + i;
    const int py = u & 1;
    const int r  = (u >> 1) + 1;
    const size_t base = (size_t)r * 136 + 4 * t;
    const U4 ev = *(const U4*)(C + ((size_t)(py * 2 + 0) * OCN + oc) * NROW + base);
    const U4 ov = *(const U4*)(C + ((size_t)(py * 2 + 1) * OCN + oc) * NROW + base);
    float E[8], O[8];
#pragma unroll
    for (int j = 0; j < 4; ++j) {
      E[2 * j]     = __uint_as_float(ev.w[j] << 16);
      E[2 * j + 1] = __uint_as_float(ev.w[j] & 0xffff0000u);
      O[2 * j]     = __uint_as_float(ov.w[j] << 16);
      O[2 * j + 1] = __uint_as_float(ov.w[j] & 0xffff0000u);
    }
    const float cv = cfv[i];
#pragma unroll
    for (int s = 0; s < 8; ++s) {
      float h;
      if ((s & 1) == 0) {
        const int k = s >> 1;
        h = 0.75f * E[k + 1] + 0.25f * E[k + 2] + 0.25f * O[k] + 0.75f * O[k + 1];
      } else {
        const int k = (s + 1) >> 1;
        h = 0.25f * E[k] + 0.75f * E[k + 1] + 0.75f * O[k] + 0.25f * O[k + 1];
      }
      acc[s] += cv * h;
    }
  }

  float* op = out + ((size_t)oc * 256 + m) * 256 + 8 * t;
  f32x4 s0 = {acc[0], acc[1], acc[2], acc[3]};
  f32x4 s1 = {acc[4], acc[5], acc[6], acc[7]};
  *(f32x4*)op = s0;
  *(f32x4*)(op + 4) = s1;
}

extern "C" void kernel_launch(void* const* d_in, const int* in_sizes, int n_in,
                              void* d_out, int out_size, void* d_ws, size_t ws_size,
                              hipStream_t stream) {
  const float* x = (const float*)d_in[0];
  const float* w = (const float*)d_in[1];
  float* out = (float*)d_out;

  // ws layout (bytes):
  //   AF : 9*32*16*1024  = 4,718,592    @ 0
  //   XPT: 17936*512*2   = 18,366,464   @ 4,718,592
  //   C  : 4*512*17792*2 = 72,876,032   @ 23,085,056   (total ~96.0 MB)
  __hip_bfloat16* AF  = (__hip_bfloat16*)d_ws;
  __hip_bfloat16* XPT = (__hip_bfloat16*)((char*)d_ws + 4718592);
  __hip_bfloat16* C   = (__hip_bfloat16*)((char*)d_ws + 23085056);

  wprep_k<<<512, 256, 0, stream>>>(w, AF);
  zguard_k<<<256, 256, 0, stream>>>((unsigned int*)XPT);
  packx2_k<<<dim3(130, 8), 256, 0, stream>>>(x, (unsigned int*)XPT);
  gemm_k<<<dim3(70, 4, 4), 512, 0, stream>>>(AF, XPT, C);
  blur2_k<<<dim3(32, 512), 256, 0, stream>>>((const unsigned short*)C, out);
}

// Round 18
// 153.681 us; speedup vs baseline: 1.1526x; 1.1526x over previous
//
#include <hip/hip_runtime.h>
#include <hip/hip_bf16.h>

#define ICN 512
#define OCN 512
#define RS    136      // padded pixel-plane row stride (cols)
#define NROW  17792    // GEMM N cols = 139*128; C plane stride
#define GUARD 144      // zero guard rows in front of XPT (max shift 137)
#define XROWS 17936    // GUARD + NROW

typedef __attribute__((ext_vector_type(8))) short short8;
typedef __attribute__((ext_vector_type(4))) float f32x4;

__device__ __forceinline__ void gload_lds16(const void* g, void* l) {
  __builtin_amdgcn_global_load_lds(
      (const __attribute__((address_space(1))) void*)g,
      (__attribute__((address_space(3))) void*)l, 16, 0, 0);
}

// raw barrier: execution sync WITHOUT vmcnt drain; compiler fences pin LDS ops
__device__ __forceinline__ void bar_raw() {
  asm volatile("" ::: "memory");
  __builtin_amdgcn_s_barrier();
  asm volatile("" ::: "memory");
}

#define SB0() __builtin_amdgcn_sched_barrier(0)

// ---- fused demod + weight pack: AP[tp][oc][ic] = coef[oc]*w[oc][ic][widx(tp)] ----
__global__ __launch_bounds__(256) void wprep_k(const float* __restrict__ w,
                                               __hip_bfloat16* __restrict__ AP) {
  constexpr int WIDX[9] = {0, 2, 6, 8, 1, 7, 3, 5, 4};  // tap -> ky*3+kx
  const int oc = blockIdx.x;
  const int tid = threadIdx.x, lane = tid & 63, wv = tid >> 6;

  float v[2][9];
  float s = 0.f;
#pragma unroll
  for (int rep = 0; rep < 2; ++rep) {
    const int ic = tid + rep * 256;
    const float* wp = w + ((size_t)oc * ICN + ic) * 9;
#pragma unroll
    for (int j = 0; j < 9; ++j) { v[rep][j] = wp[j]; s += wp[j] * wp[j]; }
  }
#pragma unroll
  for (int o = 32; o > 0; o >>= 1) s += __shfl_down(s, o, 64);
  __shared__ float red[4];
  if (lane == 0) red[wv] = s;
  __syncthreads();
  const float tot = red[0] + red[1] + red[2] + red[3];
  const float scale2 = 1.0f / 4608.0f;
  const float c = sqrtf(scale2) * rsqrtf(scale2 * tot + 1e-8f);

#pragma unroll
  for (int rep = 0; rep < 2; ++rep) {
    const int ic = tid + rep * 256;
#pragma unroll
    for (int tp = 0; tp < 9; ++tp)
      AP[((size_t)tp * OCN + oc) * ICN + ic] = __float2bfloat16(c * v[rep][WIDX[tp]]);
  }
}

// ---- x -> bf16 transposed padded pixel space, via LDS transpose tile ----
__global__ __launch_bounds__(256) void packx2_k(const float* __restrict__ x,
                                                unsigned int* __restrict__ XP32) {
  const int py  = blockIdx.x;        // 0..129
  const int ic0 = blockIdx.y * 64;
  const int tid = threadIdx.x;
  const int yy  = py - 1;
  const bool rowvalid = (unsigned)yy < 128u;

  __shared__ __hip_bfloat16 T[128 * 65];   // T[xx][ic_i], padded stride 65

  if (rowvalid) {
    const float4* xr = (const float4*)(x + (size_t)ic0 * 16384 + (size_t)yy * 128);
#pragma unroll
    for (int rep = 0; rep < 8; ++rep) {
      const int idx = rep * 256 + tid;     // 0..2047
      const int x4 = idx & 31, ici = idx >> 5;
      const float4 v = xr[(size_t)ici * 4096 + x4];   // coalesced 16B/lane
      const int xx = x4 * 4;
      T[(xx + 0) * 65 + ici] = __float2bfloat16(v.x);
      T[(xx + 1) * 65 + ici] = __float2bfloat16(v.y);
      T[(xx + 2) * 65 + ici] = __float2bfloat16(v.z);
      T[(xx + 3) * 65 + ici] = __float2bfloat16(v.w);
    }
  }
  __syncthreads();

  const size_t rowbase = (size_t)(GUARD + py * 136) * 256 + (ic0 >> 1);
  for (int rep = 0; rep < 17; ++rep) {
    const int idx = rep * 256 + tid;
    const int px = idx >> 5, j = idx & 31;
    unsigned int uv = 0;
    if (rowvalid && (unsigned)(px - 1) < 128u) {
      union { __hip_bfloat16 h[2]; unsigned int u; } cv;
      cv.h[0] = T[(px - 1) * 65 + 2 * j];
      cv.h[1] = T[(px - 1) * 65 + 2 * j + 1];
      uv = cv.u;
    }
    XP32[rowbase + (size_t)px * 256 + j] = uv;   // coalesced
  }
}

// ---- zero the guard rows [0,144) and tail rows [17824,17936) of XPT ----
__global__ __launch_bounds__(256) void zguard_k(unsigned int* __restrict__ XP32) {
  const int r = blockIdx.x;                       // 0..255
  const int row = (r < 144) ? r : (r + 17680);    // 144->17824 .. 255->17935
  XP32[(size_t)row * 256 + threadIdx.x] = 0;
}

// ---- MFMA implicit GEMM: 3-deep circular pipeline, counted vmcnt(4) ----
// BM=BN=256, BK=32 (64B LDS rows), 8 waves (2Mx4N), per-wave 128x64 out.
// 3 LDS buffers (96KB) rotate: step t reads buf[t%3], stages tile t+2 into
// buf[(t+2)%3] (4 gloads), waits vmcnt(4) at step end -- this step's loads
// stay in flight ACROSS the barrier; only tile t+1 (issued a full step ago)
// must have landed. One barrier per step. Swizzle col^=(((row>>1)&3)<<4)
// within 64B rows -> 2-way-only bank aliasing (free); linear LDS dest +
// pre-swizzled per-lane global source (involution).
__global__ __launch_bounds__(512, 2) void gemm_k(const __hip_bfloat16* __restrict__ AP,
                                                 const __hip_bfloat16* __restrict__ XPT,
                                                 __hip_bfloat16* __restrict__ C) {
  constexpr int NTt[4]   = {4, 2, 2, 1};
  constexpr int TPO[4]   = {0, 4, 6, 8};
  constexpr int SHIFT[9] = {0, 1, 136, 137, 0, 136, 0, 1, 0};
  constexpr int AR[4]    = {129, 129, 128, 128};
  constexpr int AC[4]    = {129, 128, 129, 128};

  const int n0 = blockIdx.x * 256, oc0 = blockIdx.y * 256, ph = blockIdx.z;
  const int tid = threadIdx.x, lane = tid & 63, wv = tid >> 6;
  const int wr = wv >> 2, wc = wv & 3;            // 2M x 4N wave grid
  const int lane15 = lane & 15;
  const int kx = (lane >> 4) * 16;                // k-byte offset of lane chunk

  // lds[buf]: A 16KB (256 rows x 64B) | B 16KB
  __shared__ __align__(16) char lds[3 * 32768];

  const int T2 = NTt[ph] * 16;                    // K-steps of 32

  // staging geometry: 512 threads x 16B cover one 8KB half per gload
  const int sr = tid >> 2;                        // row 0..127
  const int sc = ((tid & 3) * 16) ^ (((sr >> 1) & 3) << 4);  // pre-swizzled col

  auto STG = [&](int i, char* Lb) {               // tile i -> buffer (4 gloads)
    const int tp = TPO[ph] + (i >> 4);
    const size_t kb = (size_t)(i & 15) * 64;
    const char* Ag = (const char*)AP + (size_t)tp * (512 * 1024) +
                     (size_t)oc0 * 1024 + kb;
    const char* Bg = (const char*)XPT +
                     (size_t)(GUARD + n0 - SHIFT[tp]) * 1024 + kb;
#pragma unroll
    for (int g = 0; g < 2; ++g) {
      gload_lds16(Ag + (size_t)(g * 128 + sr) * 1024 + sc,
                  Lb + g * 8192 + wv * 1024);
      gload_lds16(Bg + (size_t)(g * 128 + sr) * 1024 + sc,
                  Lb + 16384 + g * 8192 + wv * 1024);
    }
  };

  f32x4 acc[8][4];
#pragma unroll
  for (int m = 0; m < 8; ++m)
#pragma unroll
    for (int n = 0; n < 4; ++n) acc[m][n] = (f32x4){0.f, 0.f, 0.f, 0.f};

  STG(0, lds);
  STG(1, lds + 32768);
  asm volatile("s_waitcnt vmcnt(4)" ::: "memory");   // tile 0 landed
  bar_raw();

#define DSR(dst, base, row)                                                  \
  { const int e_ = (row) * 64 + kx;                                          \
    dst = *(const short8*)((base) + (e_ ^ ((((row) >> 1) & 3) << 4))); }

#define MFMA8(mb, afv)                                                       \
  _Pragma("unroll") for (int j = 0; j < 2; ++j)                              \
  _Pragma("unroll") for (int n = 0; n < 4; ++n)                              \
    acc[(mb) + j][n] = __builtin_amdgcn_mfma_f32_16x16x32_bf16(              \
        afv[j], bf[n], acc[(mb) + j][n], 0, 0, 0);

  for (int t = 0; t < T2; ++t) {
    const char* LA = lds + (t % 3) * 32768 + wr * 8192;   // wave's 128 A rows
    const char* LB = lds + (t % 3) * 32768 + 16384;
    char* Ln = lds + ((t + 2) % 3) * 32768;
    const int ts = (t + 2 < T2) ? (t + 2) : (T2 - 1);     // tail: dummy re-stage

    short8 bf[4], afA[2], afB[2];

    // cluster 0 issue: bf x4 + af(m0,m1); then stage; then af(m2,m3)
#pragma unroll
    for (int n = 0; n < 4; ++n) DSR(bf[n], LB, wc * 64 + n * 16 + lane15);
    DSR(afA[0], LA, 0 * 16 + lane15);
    DSR(afA[1], LA, 1 * 16 + lane15);
    SB0();
    STG(ts, Ln);                                          // 4 gloads fly 1+ step
    SB0();
    DSR(afB[0], LA, 2 * 16 + lane15);
    DSR(afB[1], LA, 3 * 16 + lane15);
    SB0();
    asm volatile("s_waitcnt lgkmcnt(2)");   // bf + af01 done
    SB0();
    __builtin_amdgcn_s_setprio(1); MFMA8(0, afA); __builtin_amdgcn_s_setprio(0);
    SB0();

    DSR(afA[0], LA, 4 * 16 + lane15);       // af(m4,m5)
    DSR(afA[1], LA, 5 * 16 + lane15);
    SB0();
    asm volatile("s_waitcnt lgkmcnt(2)");   // af23 done
    SB0();
    __builtin_amdgcn_s_setprio(1); MFMA8(2, afB); __builtin_amdgcn_s_setprio(0);
    SB0();

    DSR(afB[0], LA, 6 * 16 + lane15);       // af(m6,m7)
    DSR(afB[1], LA, 7 * 16 + lane15);
    SB0();
    asm volatile("s_waitcnt lgkmcnt(2)");   // af45 done
    SB0();
    __builtin_amdgcn_s_setprio(1); MFMA8(4, afA); __builtin_amdgcn_s_setprio(0);
    SB0();

    asm volatile("s_waitcnt lgkmcnt(0)");   // af67 done
    SB0();
    __builtin_amdgcn_s_setprio(1); MFMA8(6, afB); __builtin_amdgcn_s_setprio(0);

    // counted handshake: only tile t+1 must be resident; this step's 4
    // stage-loads stay in flight across the barrier.
    asm volatile("s_waitcnt vmcnt(4)" ::: "memory");
    SB0();
    bar_raw();
  }
#undef DSR
#undef MFMA8

  // epilogue: D col = lane&15, row = (lane>>4)*4 + r; mask pad cells to zero
  const int lr = (lane >> 4) * 4, lc = lane & 15;
#pragma unroll
  for (int n = 0; n < 4; ++n) {
    const int col = n0 + wc * 64 + n * 16 + lc;
    if (col < NROW) {
      const int pa = col / 136, pb = col - pa * 136;
      const bool ok = ((unsigned)(pa - 1) < (unsigned)AR[ph]) &&
                      ((unsigned)(pb - 1) < (unsigned)AC[ph]);
#pragma unroll
      for (int m = 0; m < 8; ++m)
#pragma unroll
        for (int r = 0; r < 4; ++r) {
          const int row = oc0 + wr * 128 + m * 16 + lr + r;
          C[((size_t)(ph * OCN + row)) * NROW + col] =
              __float2bfloat16(ok ? acc[m][n][r] : 0.f);
        }
    }
  }
}

// ---- vectorized depthwise 4x4 blur: 8 outputs/thread, branch-free ----
struct __align__(8) U4 { unsigned int w[4]; };

__global__ __launch_bounds__(256) void blur2_k(const unsigned short* __restrict__ C,
                                               float* __restrict__ out) {
  const int tid = threadIdx.x;
  const int t  = tid & 31;                  // col block: n in [8t, 8t+8)
  const int m  = blockIdx.x * 8 + (tid >> 5);
  const int oc = blockIdx.y;
  const float cfv[4] = {0.25f, 0.75f, 0.75f, 0.25f};

  float acc[8];
#pragma unroll
  for (int s = 0; s < 8; ++s) acc[s] = 0.f;

#pragma unroll
  for (int i = 0; i < 4; ++i) {
    const int u  = m - 1 + i;
    const int py = u & 1;
    const int r  = (u >> 1) + 1;
    const size_t base = (size_t)r * 136 + 4 * t;
    const U4 ev = *(const U4*)(C + ((size_t)(py * 2 + 0) * OCN + oc) * NROW + base);
    const U4 ov = *(const U4*)(C + ((size_t)(py * 2 + 1) * OCN + oc) * NROW + base);
    float E[8], O[8];
#pragma unroll
    for (int j = 0; j < 4; ++j) {
      E[2 * j]     = __uint_as_float(ev.w[j] << 16);
      E[2 * j + 1] = __uint_as_float(ev.w[j] & 0xffff0000u);
      O[2 * j]     = __uint_as_float(ov.w[j] << 16);
      O[2 * j + 1] = __uint_as_float(ov.w[j] & 0xffff0000u);
    }
    const float cv = cfv[i];
#pragma unroll
    for (int s = 0; s < 8; ++s) {
      float h;
      if ((s & 1) == 0) {
        const int k = s >> 1;
        h = 0.75f * E[k + 1] + 0.25f * E[k + 2] + 0.25f * O[k] + 0.75f * O[k + 1];
      } else {
        const int k = (s + 1) >> 1;
        h = 0.25f * E[k] + 0.75f * E[k + 1] + 0.75f * O[k] + 0.25f * O[k + 1];
      }
      acc[s] += cv * h;
    }
  }

  float* op = out + ((size_t)oc * 256 + m) * 256 + 8 * t;
  f32x4 s0 = {acc[0], acc[1], acc[2], acc[3]};
  f32x4 s1 = {acc[4], acc[5], acc[6], acc[7]};
  *(f32x4*)op = s0;
  *(f32x4*)(op + 4) = s1;
}

extern "C" void kernel_launch(void* const* d_in, const int* in_sizes, int n_in,
                              void* d_out, int out_size, void* d_ws, size_t ws_size,
                              hipStream_t stream) {
  const float* x = (const float*)d_in[0];
  const float* w = (const float*)d_in[1];
  float* out = (float*)d_out;

  // ws layout (bytes):
  //   AP : 9*512*512*2   = 4,718,592    @ 0
  //   XPT: 17936*512*2   = 18,366,464   @ 4,718,592
  //   C  : 4*512*17792*2 = 72,876,032   @ 23,085,056   (total ~96.0 MB)
  __hip_bfloat16* AP  = (__hip_bfloat16*)d_ws;
  __hip_bfloat16* XPT = (__hip_bfloat16*)((char*)d_ws + 4718592);
  __hip_bfloat16* C   = (__hip_bfloat16*)((char*)d_ws + 23085056);

  wprep_k<<<512, 256, 0, stream>>>(w, AP);
  zguard_k<<<256, 256, 0, stream>>>((unsigned int*)XPT);
  packx2_k<<<dim3(130, 8), 256, 0, stream>>>(x, (unsigned int*)XPT);
  gemm_k<<<dim3(70, 2, 4), 512, 0, stream>>>(AP, XPT, C);
  blur2_k<<<dim3(32, 512), 256, 0, stream>>>((const unsigned short*)C, out);
}

// Round 21
// 146.079 us; speedup vs baseline: 1.2126x; 1.0520x over previous
//
#include <hip/hip_runtime.h>
#include <hip/hip_bf16.h>

#define ICN 512
#define OCN 512
#define RS    136      // padded pixel-plane row stride (cols)
#define NROW  17792    // GEMM N cols = 139*128; C plane stride
#define GUARD 144      // zero guard rows in front of XPT (max shift 137)
#define XROWS 17936    // GUARD + NROW

typedef __attribute__((ext_vector_type(8))) short short8;
typedef __attribute__((ext_vector_type(4))) float f32x4;

__device__ __forceinline__ void gload_lds16(const void* g, void* l) {
  __builtin_amdgcn_global_load_lds(
      (const __attribute__((address_space(1))) void*)g,
      (__attribute__((address_space(3))) void*)l, 16, 0, 0);
}

// raw barrier: execution sync WITHOUT vmcnt drain; compiler fences pin LDS ops
__device__ __forceinline__ void bar_raw() {
  asm volatile("" ::: "memory");
  __builtin_amdgcn_s_barrier();
  asm volatile("" ::: "memory");
}

#define SB0() __builtin_amdgcn_sched_barrier(0)

// ---- fused demod + weight pack: AP[tp][oc][ic] = coef[oc]*w[oc][ic][widx(tp)] ----
__global__ __launch_bounds__(256) void wprep_k(const float* __restrict__ w,
                                               __hip_bfloat16* __restrict__ AP) {
  constexpr int WIDX[9] = {0, 2, 6, 8, 1, 7, 3, 5, 4};  // tap -> ky*3+kx
  const int oc = blockIdx.x;
  const int tid = threadIdx.x, lane = tid & 63, wv = tid >> 6;

  float v[2][9];
  float s = 0.f;
#pragma unroll
  for (int rep = 0; rep < 2; ++rep) {
    const int ic = tid + rep * 256;
    const float* wp = w + ((size_t)oc * ICN + ic) * 9;
#pragma unroll
    for (int j = 0; j < 9; ++j) { v[rep][j] = wp[j]; s += wp[j] * wp[j]; }
  }
#pragma unroll
  for (int o = 32; o > 0; o >>= 1) s += __shfl_down(s, o, 64);
  __shared__ float red[4];
  if (lane == 0) red[wv] = s;
  __syncthreads();
  const float tot = red[0] + red[1] + red[2] + red[3];
  const float scale2 = 1.0f / 4608.0f;
  const float c = sqrtf(scale2) * rsqrtf(scale2 * tot + 1e-8f);

#pragma unroll
  for (int rep = 0; rep < 2; ++rep) {
    const int ic = tid + rep * 256;
#pragma unroll
    for (int tp = 0; tp < 9; ++tp)
      AP[((size_t)tp * OCN + oc) * ICN + ic] = __float2bfloat16(c * v[rep][WIDX[tp]]);
  }
}

// ---- x -> bf16 transposed padded pixel space, via LDS transpose tile ----
__global__ __launch_bounds__(256) void packx2_k(const float* __restrict__ x,
                                                unsigned int* __restrict__ XP32) {
  const int py  = blockIdx.x;        // 0..129
  const int ic0 = blockIdx.y * 64;
  const int tid = threadIdx.x;
  const int yy  = py - 1;
  const bool rowvalid = (unsigned)yy < 128u;

  __shared__ __hip_bfloat16 T[128 * 65];   // T[xx][ic_i], padded stride 65

  if (rowvalid) {
    const float4* xr = (const float4*)(x + (size_t)ic0 * 16384 + (size_t)yy * 128);
#pragma unroll
    for (int rep = 0; rep < 8; ++rep) {
      const int idx = rep * 256 + tid;     // 0..2047
      const int x4 = idx & 31, ici = idx >> 5;
      const float4 v = xr[(size_t)ici * 4096 + x4];   // coalesced 16B/lane
      const int xx = x4 * 4;
      T[(xx + 0) * 65 + ici] = __float2bfloat16(v.x);
      T[(xx + 1) * 65 + ici] = __float2bfloat16(v.y);
      T[(xx + 2) * 65 + ici] = __float2bfloat16(v.z);
      T[(xx + 3) * 65 + ici] = __float2bfloat16(v.w);
    }
  }
  __syncthreads();

  const size_t rowbase = (size_t)(GUARD + py * 136) * 256 + (ic0 >> 1);
  for (int rep = 0; rep < 17; ++rep) {
    const int idx = rep * 256 + tid;
    const int px = idx >> 5, j = idx & 31;
    unsigned int uv = 0;
    if (rowvalid && (unsigned)(px - 1) < 128u) {
      union { __hip_bfloat16 h[2]; unsigned int u; } cv;
      cv.h[0] = T[(px - 1) * 65 + 2 * j];
      cv.h[1] = T[(px - 1) * 65 + 2 * j + 1];
      uv = cv.u;
    }
    XP32[rowbase + (size_t)px * 256 + j] = uv;   // coalesced
  }
}

// ---- zero the guard rows [0,144) and tail rows [17824,17936) of XPT ----
__global__ __launch_bounds__(256) void zguard_k(unsigned int* __restrict__ XP32) {
  const int r = blockIdx.x;                       // 0..255
  const int row = (r < 144) ? r : (r + 17680);    // 144->17824 .. 255->17935
  XP32[(size_t)row * 256 + threadIdx.x] = 0;
}

// ---- MFMA implicit GEMM: fine 8-cluster interleave, 1 barrier per K-step ----
// BM=BN=256, BK=64 (128B LDS rows), 8 waves (2Mx4N), per-wave 128x64 out.
// Per K-step: 8 clusters of {<=2 ds_read issue -> lgkmcnt(2) lookahead ->
// 8 MFMA}; ALL 8 stage gloads issued in one burst right after cluster I0
// (full-step flight time before the end-of-step vmcnt(0)); single
// vmcnt(0)+s_barrier per K-step. Swizzle byte^=((row&7)<<4); linear LDS
// dest + pre-swizzled global source.
__global__ __launch_bounds__(512, 2) void gemm_k(const __hip_bfloat16* __restrict__ AP,
                                                 const __hip_bfloat16* __restrict__ XPT,
                                                 __hip_bfloat16* __restrict__ C) {
  constexpr int NTt[4]   = {4, 2, 2, 1};
  constexpr int TPO[4]   = {0, 4, 6, 8};
  constexpr int SHIFT[9] = {0, 1, 136, 137, 0, 136, 0, 1, 0};
  constexpr int AR[4]    = {129, 129, 128, 128};
  constexpr int AC[4]    = {129, 128, 129, 128};

  const int n0 = blockIdx.x * 256, oc0 = blockIdx.y * 256, ph = blockIdx.z;
  const int tid = threadIdx.x, lane = tid & 63, wv = tid >> 6;
  const int wr = wv >> 2, wc = wv & 3;            // 2M x 4N wave grid
  const int lane15 = lane & 15, l7 = lane & 7;
  const int kx = (lane >> 4) * 16;                // k-byte offset of lane chunk

  // lds[buf]: A half0 16K | A half1 16K | B half0 16K | B half1 16K
  __shared__ __align__(16) char lds[2 * 65536];

  const int T = NTt[ph] * 8;                      // K-steps of 64

  // staging geometry (uniform per thread across steps)
  const int r0  = tid >> 3;                       // base row 0..63
  const int wk0 = ((tid * 16) & 127) ^ ((r0 & 7) << 4);

  auto STG = [&](const char* Ag, const char* Bg, char* Lnext, int g) {
    const int hh = (g >> 1) & 1, c = g & 1;
    if (g < 4)
      gload_lds16(Ag + (size_t)(hh * 128 + r0 + c * 64) * 1024 + wk0,
                  Lnext + hh * 16384 + c * 8192 + wv * 1024);
    else
      gload_lds16(Bg + (size_t)(hh * 128 + r0 + c * 64) * 1024 + wk0,
                  Lnext + 32768 + hh * 16384 + c * 8192 + wv * 1024);
  };

  f32x4 acc[8][4];
#pragma unroll
  for (int m = 0; m < 8; ++m)
#pragma unroll
    for (int n = 0; n < 4; ++n) acc[m][n] = (f32x4){0.f, 0.f, 0.f, 0.f};

  // prologue: full stage of tile 0
  {
    const int tp = TPO[ph];
    const char* Ag = (const char*)AP + (size_t)tp * (512 * 1024) + (size_t)oc0 * 1024;
    const char* Bg = (const char*)XPT + (size_t)(GUARD + n0 - SHIFT[tp]) * 1024;
#pragma unroll
    for (int g = 0; g < 8; ++g) STG(Ag, Bg, lds, g);
  }
  asm volatile("s_waitcnt vmcnt(0)" ::: "memory");
  bar_raw();

#define DSR(dst, base, row, khh)                                            \
  { const int e_ = (row) * 128 + (khh) * 64 + kx;                           \
    dst = *(const short8*)((base) + (e_ ^ (l7 << 4))); }

#define MFMA8(mb, afv, bfv)                                                 \
  _Pragma("unroll") for (int j = 0; j < 2; ++j)                             \
  _Pragma("unroll") for (int n = 0; n < 4; ++n)                             \
    acc[(mb) + j][n] = __builtin_amdgcn_mfma_f32_16x16x32_bf16(             \
        afv[j], bfv[n], acc[(mb) + j][n], 0, 0, 0);

  for (int t = 0; t < T; ++t) {
    const int buf = t & 1;
    const char* LA = lds + buf * 65536 + wr * 16384;            // wave's A half
    const char* LB = lds + buf * 65536 + 32768 + (wc >> 1) * 16384;
    const int brow = (wc & 1) * 64;
    char* Lnext = lds + (buf ^ 1) * 65536;
    const int ts = (t + 1 < T) ? (t + 1) : (T - 1);             // tail: dummy
    const int tp = TPO[ph] + (ts >> 3);
    const size_t kb = (size_t)(ts & 7) * 128;
    const char* Ag = (const char*)AP + (size_t)tp * (512 * 1024) +
                     (size_t)oc0 * 1024 + kb;
    const char* Bg = (const char*)XPT +
                     (size_t)(GUARD + n0 - SHIFT[tp]) * 1024 + kb;

    short8 bf0[4], bf1[4], afA[2], afB[2];

    // I0: bf(kh0) x4 + af(m01,kh0) x2
#pragma unroll
    for (int n = 0; n < 4; ++n) DSR(bf0[n], LB, brow + n * 16 + lane15, 0);
    DSR(afA[0], LA, 0 * 16 + lane15, 0);
    DSR(afA[1], LA, 1 * 16 + lane15, 0);
    SB0();
    // hoisted stage burst: all 8 gloads fly for the whole step
#pragma unroll
    for (int g = 0; g < 8; ++g) STG(Ag, Bg, Lnext, g);
    SB0();
    // I1: bf(kh1) x4 + af(m01,kh1) x2
#pragma unroll
    for (int n = 0; n < 4; ++n) DSR(bf1[n], LB, brow + n * 16 + lane15, 1);
    DSR(afB[0], LA, 0 * 16 + lane15, 1);
    DSR(afB[1], LA, 1 * 16 + lane15, 1);
    SB0();
    asm volatile("s_waitcnt lgkmcnt(6)");   // I0 ready
    SB0();
    __builtin_amdgcn_s_setprio(1); MFMA8(0, afA, bf0); __builtin_amdgcn_s_setprio(0);
    SB0();

    DSR(afA[0], LA, 2 * 16 + lane15, 0);    // I2: af(m23,kh0)
    DSR(afA[1], LA, 3 * 16 + lane15, 0);
    SB0();
    asm volatile("s_waitcnt lgkmcnt(2)");   // I1 ready
    SB0();
    __builtin_amdgcn_s_setprio(1); MFMA8(0, afB, bf1); __builtin_amdgcn_s_setprio(0);
    SB0();

    DSR(afB[0], LA, 2 * 16 + lane15, 1);    // I3: af(m23,kh1)
    DSR(afB[1], LA, 3 * 16 + lane15, 1);
    SB0();
    asm volatile("s_waitcnt lgkmcnt(2)");   // I2 ready
    SB0();
    __builtin_amdgcn_s_setprio(1); MFMA8(2, afA, bf0); __builtin_amdgcn_s_setprio(0);
    SB0();

    DSR(afA[0], LA, 4 * 16 + lane15, 0);    // I4: af(m45,kh0)
    DSR(afA[1], LA, 5 * 16 + lane15, 0);
    SB0();
    asm volatile("s_waitcnt lgkmcnt(2)");   // I3 ready
    SB0();
    __builtin_amdgcn_s_setprio(1); MFMA8(2, afB, bf1); __builtin_amdgcn_s_setprio(0);
    SB0();

    DSR(afB[0], LA, 4 * 16 + lane15, 1);    // I5: af(m45,kh1)
    DSR(afB[1], LA, 5 * 16 + lane15, 1);
    SB0();
    asm volatile("s_waitcnt lgkmcnt(2)");   // I4 ready
    SB0();
    __builtin_amdgcn_s_setprio(1); MFMA8(4, afA, bf0); __builtin_amdgcn_s_setprio(0);
    SB0();

    DSR(afA[0], LA, 6 * 16 + lane15, 0);    // I6: af(m67,kh0)
    DSR(afA[1], LA, 7 * 16 + lane15, 0);
    SB0();
    asm volatile("s_waitcnt lgkmcnt(2)");   // I5 ready
    SB0();
    __builtin_amdgcn_s_setprio(1); MFMA8(4, afB, bf1); __builtin_amdgcn_s_setprio(0);
    SB0();

    DSR(afB[0], LA, 6 * 16 + lane15, 1);    // I7: af(m67,kh1)
    DSR(afB[1], LA, 7 * 16 + lane15, 1);
    SB0();
    asm volatile("s_waitcnt lgkmcnt(2)");   // I6 ready
    SB0();
    __builtin_amdgcn_s_setprio(1); MFMA8(6, afA, bf0); __builtin_amdgcn_s_setprio(0);
    SB0();

    asm volatile("s_waitcnt lgkmcnt(0)");   // I7 ready (all reads done)
    SB0();
    __builtin_amdgcn_s_setprio(1); MFMA8(6, afB, bf1); __builtin_amdgcn_s_setprio(0);

    // single cross-wave handshake: my reads done + my stage landed
    asm volatile("s_waitcnt vmcnt(0)" ::: "memory");
    SB0();
    bar_raw();
  }
#undef DSR
#undef MFMA8

  // epilogue: D col = lane&15, row = (lane>>4)*4 + r; mask pad cells to zero
  const int lr = (lane >> 4) * 4, lc = lane & 15;
#pragma unroll
  for (int n = 0; n < 4; ++n) {
    const int col = n0 + wc * 64 + n * 16 + lc;
    if (col < NROW) {
      const int pa = col / 136, pb = col - pa * 136;
      const bool ok = ((unsigned)(pa - 1) < (unsigned)AR[ph]) &&
                      ((unsigned)(pb - 1) < (unsigned)AC[ph]);
#pragma unroll
      for (int m = 0; m < 8; ++m)
#pragma unroll
        for (int r = 0; r < 4; ++r) {
          const int row = oc0 + wr * 128 + m * 16 + lr + r;
          C[((size_t)(ph * OCN + row)) * NROW + col] =
              __float2bfloat16(ok ? acc[m][n][r] : 0.f);
        }
    }
  }
}

// ---- vectorized depthwise 4x4 blur: 8 outputs/thread, branch-free ----
struct __align__(8) U4 { unsigned int w[4]; };

__global__ __launch_bounds__(256) void blur2_k(const unsigned short* __restrict__ C,
                                               float* __restrict__ out) {
  const int tid = threadIdx.x;
  const int t  = tid & 31;                  // col block: n in [8t, 8t+8)
  const int m  = blockIdx.x * 8 + (tid >> 5);
  const int oc = blockIdx.y;
  const float cfv[4] = {0.25f, 0.75f, 0.75f, 0.25f};

  float acc[8];
#pragma unroll
  for (int s = 0; s < 8; ++s) acc[s] = 0.f;

#pragma unroll
  for (int i = 0; i < 4; ++i) {
    const int u  = m - 1 + i;
    const int py = u & 1;
    const int r  = (u >> 1) + 1;
    const size_t base = (size_t)r * 136 + 4 * t;
    const U4 ev = *(const U4*)(C + ((size_t)(py * 2 + 0) * OCN + oc) * NROW + base);
    const U4 ov = *(const U4*)(C + ((size_t)(py * 2 + 1) * OCN + oc) * NROW + base);
    float E[8], O[8];
#pragma unroll
    for (int j = 0; j < 4; ++j) {
      E[2 * j]     = __uint_as_float(ev.w[j] << 16);
      E[2 * j + 1] = __uint_as_float(ev.w[j] & 0xffff0000u);
      O[2 * j]     = __uint_as_float(ov.w[j] << 16);
      O[2 * j + 1] = __uint_as_float(ov.w[j] & 0xffff0000u);
    }
    const float cv = cfv[i];
#pragma unroll
    for (int s = 0; s < 8; ++s) {
      float h;
      if ((s & 1) == 0) {
        const int k = s >> 1;
        h = 0.75f * E[k + 1] + 0.25f * E[k + 2] + 0.25f * O[k] + 0.75f * O[k + 1];
      } else {
        const int k = (s + 1) >> 1;
        h = 0.25f * E[k] + 0.75f * E[k + 1] + 0.75f * O[k] + 0.25f * O[k + 1];
      }
      acc[s] += cv * h;
    }
  }

  float* op = out + ((size_t)oc * 256 + m) * 256 + 8 * t;
  f32x4 s0 = {acc[0], acc[1], acc[2], acc[3]};
  f32x4 s1 = {acc[4], acc[5], acc[6], acc[7]};
  *(f32x4*)op = s0;
  *(f32x4*)(op + 4) = s1;
}

extern "C" void kernel_launch(void* const* d_in, const int* in_sizes, int n_in,
                              void* d_out, int out_size, void* d_ws, size_t ws_size,
                              hipStream_t stream) {
  const float* x = (const float*)d_in[0];
  const float* w = (const float*)d_in[1];
  float* out = (float*)d_out;

  // ws layout (bytes):
  //   AP : 9*512*512*2   = 4,718,592    @ 0
  //   XPT: 17936*512*2   = 18,366,464   @ 4,718,592
  //   C  : 4*512*17792*2 = 72,876,032   @ 23,085,056   (total ~96.0 MB)
  __hip_bfloat16* AP  = (__hip_bfloat16*)d_ws;
  __hip_bfloat16* XPT = (__hip_bfloat16*)((char*)d_ws + 4718592);
  __hip_bfloat16* C   = (__hip_bfloat16*)((char*)d_ws + 23085056);

  wprep_k<<<512, 256, 0, stream>>>(w, AP);
  zguard_k<<<256, 256, 0, stream>>>((unsigned int*)XPT);
  packx2_k<<<dim3(130, 8), 256, 0, stream>>>(x, (unsigned int*)XPT);
  gemm_k<<<dim3(70, 2, 4), 512, 0, stream>>>(AP, XPT, C);
  blur2_k<<<dim3(32, 512), 256, 0, stream>>>((const unsigned short*)C, out);
}